// Round 2
// baseline (95.809 us; speedup 1.0000x reference)
//
#include <hip/hip_runtime.h>
#include <stdint.h>

// SampleChamfer: out = sum_i min_k ||pa_i - pb_k||^2
// pa_i = a[:, a_idx[i]], pb_k = b[:, b_idx[k]], fp32 scalar out.
//
// R6: barrier-free M + single-pass fold. Post-mortem of R5: removing the 1M
// atomicMins made things WORSE (69.7 -> 75.8), so atomics were never the
// bottleneck; R5's barrier-per-chunk LDS pipeline at 2 blocks/CU was. The
// compute floor is ~3.4 us (268M lane-ops), so structure must maximize
// occupancy and kill all in-loop sync. 2 dispatches:
//  P: gather ONCE -> pa4[i]=(ax,ay,az,||a||^2), pb4[i]=(-2bx,-2by,-2bz,||b||^2);
//     zeroes the fold ticket. (64 blocks x 128 threads)
//  M: 1024 blocks x 256 threads (4 blocks/CU, 16 waves/CU). Each block owns
//     8 a-points in registers; streams ALL 8192 b-points straight from global
//     (pb4[j*256+t]: coalesced float4, L2-broadcast across blocks, 32 VALU ops
//     per 16B load => VALU-bound, NO LDS tile, NO barriers in the hot loop).
//     Epilogue: all-lanes shfl_xor min tree + [4][8] LDS combine + ||a||^2 +
//     8-lane sum -> one block partial. Final fold = decoupled single-pass:
//     release-store partial[bid], agent-scope ticket fetch_add; last block
//     acquire-loads the 1024 partials and plain-stores out[0] (kernel
//     boundary publishes to the checker). No minarr, no R pass, no atomicMin.

#define MT    256                 // min-kernel threads
#define APB   8                   // a-points per M block -> grid 1024

__global__ __launch_bounds__(128)
void chamfer_pack_kernel(const float* __restrict__ a,
                         const float* __restrict__ b,
                         const int* __restrict__ a_idx,
                         const int* __restrict__ b_idx,
                         float4* __restrict__ pa4,
                         float4* __restrict__ pb4,
                         unsigned* __restrict__ ticket,
                         int N, int n) {
    int i = blockIdx.x * 128 + threadIdx.x;   // 64 blocks x 128 threads
    if (i < n) {
        int ai = a_idx[i];
        float x = a[ai], y = a[N + ai], z = a[2 * N + ai];
        pa4[i] = make_float4(x, y, z, x * x + y * y + z * z);
        int bi = b_idx[i];
        float u = b[bi], v = b[N + bi], w = b[2 * N + bi];
        pb4[i] = make_float4(-2.f * u, -2.f * v, -2.f * w,
                             u * u + v * v + w * w);
    }
    if (i == 0)   // re-arm the fold ticket every iteration (graph replay)
        __hip_atomic_store(ticket, 0u, __ATOMIC_RELEASE,
                           __HIP_MEMORY_SCOPE_AGENT);
}

__global__ __launch_bounds__(MT)
void chamfer_min_kernel(const float4* __restrict__ pa4,
                        const float4* __restrict__ pb4,
                        float* __restrict__ partial,
                        unsigned* __restrict__ ticket,
                        float* __restrict__ out,
                        int n) {
    __shared__ float red[4][APB];
    __shared__ int   lastflag;

    const int t     = threadIdx.x;
    const int bid   = blockIdx.x;
    const int abase = bid * APB;

    float ax[APB], ay[APB], az[APB], mn[APB];
#pragma unroll
    for (int m = 0; m < APB; ++m) {           // uniform addr -> broadcast
        float4 p = pa4[abase + m];
        ax[m] = p.x; ay[m] = p.y; az[m] = p.z;
        mn[m] = 3.4e38f;
    }

    // Stream all b-points: thread t covers b = j*256 + t (each b exactly once
    // per block). Coalesced 4KB/wave-instr; 32 VALU ops per load.
    const int NJ = n >> 8;                    // 32
#pragma unroll 4
    for (int j = 0; j < NJ; ++j) {
        float4 bt = pb4[j * MT + t];
#pragma unroll
        for (int m = 0; m < APB; ++m) {
            float d = fmaf(bt.x, ax[m],
                      fmaf(bt.y, ay[m],
                      fmaf(bt.z, az[m], bt.w)));
            mn[m] = fminf(mn[m], d);
        }
    }

    // all-lanes wave min, then lane m of each wave deposits a-point m
#pragma unroll
    for (int m = 0; m < APB; ++m) {
        float v = mn[m];
        v = fminf(v, __shfl_xor(v, 1, 64));
        v = fminf(v, __shfl_xor(v, 2, 64));
        v = fminf(v, __shfl_xor(v, 4, 64));
        v = fminf(v, __shfl_xor(v, 8, 64));
        v = fminf(v, __shfl_xor(v, 16, 64));
        v = fminf(v, __shfl_xor(v, 32, 64));
        if ((t & 63) == m) red[t >> 6][m] = v;
    }
    __syncthreads();

    float bp = 0.f;
    if (t < APB) {                            // t == a_local
        float v = fminf(fminf(red[0][t], red[1][t]),
                        fminf(red[2][t], red[3][t]));
        v += pa4[abase + t].w;                // + ||a||^2 after the min
        v += __shfl_down(v, 4, 8);
        v += __shfl_down(v, 2, 8);
        v += __shfl_down(v, 1, 8);
        bp = v;                               // t==0 holds block partial
    }

    if (t == 0) {
        __hip_atomic_store(&partial[bid], bp, __ATOMIC_RELEASE,
                           __HIP_MEMORY_SCOPE_AGENT);
        unsigned old = __hip_atomic_fetch_add(ticket, 1u, __ATOMIC_ACQ_REL,
                                              __HIP_MEMORY_SCOPE_AGENT);
        lastflag = (old == gridDim.x - 1);
    }
    __syncthreads();

    if (lastflag) {                           // exactly one block folds
        float s = 0.f;
        for (int i = t; i < (int)gridDim.x; i += MT)
            s += __hip_atomic_load(&partial[i], __ATOMIC_ACQUIRE,
                                   __HIP_MEMORY_SCOPE_AGENT);
        s += __shfl_xor(s, 1, 64);
        s += __shfl_xor(s, 2, 64);
        s += __shfl_xor(s, 4, 64);
        s += __shfl_xor(s, 8, 64);
        s += __shfl_xor(s, 16, 64);
        s += __shfl_xor(s, 32, 64);
        if ((t & 63) == 0) red[t >> 6][0] = s;
        __syncthreads();
        if (t == 0)
            out[0] = red[0][0] + red[1][0] + red[2][0] + red[3][0];
    }
}

extern "C" void kernel_launch(void* const* d_in, const int* in_sizes, int n_in,
                              void* d_out, int out_size, void* d_ws, size_t ws_size,
                              hipStream_t stream) {
    const float* a     = (const float*)d_in[0];
    const float* b     = (const float*)d_in[1];
    const int*   a_idx = (const int*)d_in[2];
    const int*   b_idx = (const int*)d_in[3];
    float*       out   = (float*)d_out;

    const int N = in_sizes[0] / 3;   // 16384
    const int n = in_sizes[2];       // 8192

    // ws layout: pa4 [n], pb4 [n], partial [n/APB], ticket [1]
    float4*   pa4     = (float4*)d_ws;
    float4*   pb4     = pa4 + n;
    float*    partial = (float*)(pb4 + n);
    unsigned* ticket  = (unsigned*)(partial + n / APB);

    chamfer_pack_kernel<<<n / 128, 128, 0, stream>>>(
        a, b, a_idx, b_idx, pa4, pb4, ticket, N, n);

    chamfer_min_kernel<<<n / APB, MT, 0, stream>>>(
        pa4, pb4, partial, ticket, out, n);
}

// Round 3
// 81.762 us; speedup vs baseline: 1.1718x; 1.1718x over previous
//
#include <hip/hip_runtime.h>
#include <stdint.h>

// SampleChamfer: out = sum_i min_k ||pa_i - pb_k||^2
// pa_i = a[:, a_idx[i]], pb_k = b[:, b_idx[k]], fp32 scalar out.
//
// R7: R6's barrier-free streaming M, with the coherence pathology removed.
// Post-mortem chain: R5 (barrier pipeline, 2 blk/CU) 75.8; R6 (agent-scope
// ACQ_REL ticket + acquire fold) 95.8 — each agent-scope acquire invalidates
// the XCD's L2 (non-coherent across XCDs), so 1024 staggered acquires kept
// evicting pb4 out from under the other resident blocks. Lesson: relaxed
// fire-and-forget atomics are cheap (R4 did 1M); acquire semantics in the hot
// kernel are poison. Budget: ~40 us poison-fill (harness, irreducible) + P +
// M + gaps. 2 dispatches:
//  P: 128 blocks x 64 threads, one point per thread, 6-way-ILP scattered
//     gather -> pa4[i]=(ax,ay,az,||a||^2), pb4[i]=(-2bx,-2by,-2bz,||b||^2);
//     thread 0 zeroes out[0] (published to M by the kernel boundary).
//  M: 1024 blocks x 256 threads (4 blk/CU, 16 waves/CU). Each block owns 8
//     a-points in registers; streams ALL 8192 b-points from global
//     (coalesced float4, L2-broadcast across blocks, 32 VALU ops per 16B
//     load; NO LDS tile, NO barriers, NO acquires in the hot loop).
//     Epilogue: shfl_xor min tree + [4][8] LDS combine + ||a||^2 + 8-lane
//     sum -> ONE relaxed device-scope atomicAdd(out, bp) per block.

#define MT    256                 // min-kernel threads
#define APB   8                   // a-points per M block -> grid 1024

__global__ __launch_bounds__(64)
void chamfer_pack_kernel(const float* __restrict__ a,
                         const float* __restrict__ b,
                         const int* __restrict__ a_idx,
                         const int* __restrict__ b_idx,
                         float4* __restrict__ pa4,
                         float4* __restrict__ pb4,
                         float* __restrict__ out,
                         int N, int n) {
    int i = blockIdx.x * 64 + threadIdx.x;    // 128 blocks x 64 threads
    if (i < n) {
        int ai = a_idx[i];
        int bi = b_idx[i];
        // 6 independent scattered loads (ILP-6) after the two idx loads
        float x = a[ai], y = a[N + ai], z = a[2 * N + ai];
        float u = b[bi], v = b[N + bi], w = b[2 * N + bi];
        pa4[i] = make_float4(x, y, z, x * x + y * y + z * z);
        pb4[i] = make_float4(-2.f * u, -2.f * v, -2.f * w,
                             u * u + v * v + w * w);
    }
    if (i == 0) out[0] = 0.f;                 // d_out is poisoned each iter
}

__global__ __launch_bounds__(MT)
void chamfer_min_kernel(const float4* __restrict__ pa4,
                        const float4* __restrict__ pb4,
                        float* __restrict__ out,
                        int n) {
    __shared__ float red[4][APB];

    const int t     = threadIdx.x;
    const int abase = blockIdx.x * APB;

    float ax[APB], ay[APB], az[APB], mn[APB];
#pragma unroll
    for (int m = 0; m < APB; ++m) {           // uniform addr -> scalar loads
        float4 p = pa4[abase + m];
        ax[m] = p.x; ay[m] = p.y; az[m] = p.z;
        mn[m] = 3.4e38f;
    }

    // Stream all b-points: thread t covers b = j*256 + t. Coalesced 4KB per
    // wave-instr, L2-broadcast across all 1024 blocks; 32 VALU ops per load.
    const int NJ = n >> 8;                    // 32
#pragma unroll 8
    for (int j = 0; j < NJ; ++j) {
        float4 bt = pb4[j * MT + t];
#pragma unroll
        for (int m = 0; m < APB; ++m) {
            float d = fmaf(bt.x, ax[m],
                      fmaf(bt.y, ay[m],
                      fmaf(bt.z, az[m], bt.w)));
            mn[m] = fminf(mn[m], d);
        }
    }

    // all-lanes wave min; lane m of each wave deposits a-point m
#pragma unroll
    for (int m = 0; m < APB; ++m) {
        float v = mn[m];
        v = fminf(v, __shfl_xor(v, 1, 64));
        v = fminf(v, __shfl_xor(v, 2, 64));
        v = fminf(v, __shfl_xor(v, 4, 64));
        v = fminf(v, __shfl_xor(v, 8, 64));
        v = fminf(v, __shfl_xor(v, 16, 64));
        v = fminf(v, __shfl_xor(v, 32, 64));
        if ((t & 63) == m) red[t >> 6][m] = v;
    }
    __syncthreads();

    if (t < APB) {                            // t == a_local
        float v = fminf(fminf(red[0][t], red[1][t]),
                        fminf(red[2][t], red[3][t]));
        v += pa4[abase + t].w;                // + ||a||^2 after the min
        v += __shfl_down(v, 4, 8);
        v += __shfl_down(v, 2, 8);
        v += __shfl_down(v, 1, 8);
        if (t == 0)
            atomicAdd(out, v);                // relaxed, fire-and-forget
    }
}

extern "C" void kernel_launch(void* const* d_in, const int* in_sizes, int n_in,
                              void* d_out, int out_size, void* d_ws, size_t ws_size,
                              hipStream_t stream) {
    const float* a     = (const float*)d_in[0];
    const float* b     = (const float*)d_in[1];
    const int*   a_idx = (const int*)d_in[2];
    const int*   b_idx = (const int*)d_in[3];
    float*       out   = (float*)d_out;

    const int N = in_sizes[0] / 3;   // 16384
    const int n = in_sizes[2];       // 8192

    // ws layout: pa4 [n], pb4 [n]
    float4* pa4 = (float4*)d_ws;
    float4* pb4 = pa4 + n;

    chamfer_pack_kernel<<<n / 64, 64, 0, stream>>>(
        a, b, a_idx, b_idx, pa4, pb4, out, N, n);

    chamfer_min_kernel<<<n / APB, MT, 0, stream>>>(pa4, pb4, out, n);
}

// Round 4
// 69.082 us; speedup vs baseline: 1.3869x; 1.1836x over previous
//
#include <hip/hip_runtime.h>
#include <stdint.h>

// SampleChamfer: out = sum_i min_k ||pa_i - pb_k||^2
// pa_i = a[:, a_idx[i]], pb_k = b[:, b_idx[k]], fp32 scalar out.
//
// R8: revert to the R4 composition verbatim (best harness-verified: 69.7 us).
// Post-mortem chain: R5 (barrier pipeline, 2 blk/CU) 75.8; R6 (agent-scope
// acquires -> L2 thrash) 95.8; R7 (global-streaming M, 2.0 ops/B vs L2's
// ~56 B/cyc/CU supply, lost LDS reuse) 81.8. R4's M is the only structure
// that is purely VALU-bound: b-tile broadcast from LDS (conflict-free),
// a-points in registers, no in-loop barriers, 4 blk/CU, relaxed
// fire-and-forget atomicMin (1M of them measured cheap in R4).
// Budget: ~40 us harness poison-fill + ~20 us fixed reset/launch overhead
// + ~10 us kernels (P~2, M~4, R~1, gaps). 3 dispatches:
//  P: gather ONCE -> pa4[i]=(ax,ay,az,||a||^2), pb4[i]=(-2bx,-2by,-2bz,||b||^2);
//     inits minarr[i]=0xFFFFFFFF (encoded +inf), zeroes d_out.
//  M: grid 8 a-chunks x 128 b-chunks = 1024 blocks (4/CU). 64 b-points in LDS,
//     4 a-points/thread in registers; cross-b-chunk combine via fire-and-forget
//     device-scope atomicMin on an order-preserving uint encoding (exact:
//     integer min is associative; deterministic).
//  R: 32 blocks decode minarr (plain loads — kernel boundary publishes),
//     add ||a||^2, block-sum, atomicAdd -> pre-zeroed d_out.

#define BLOCK   256
#define NPTS_A  4     // a-points per thread -> 1024 a-points/block, 8 a-chunks
#define BPTS    64    // b-points per block  -> 128 b-chunks; grid = 1024

// Order-preserving float -> uint32 (monotone for all floats incl. negatives)
__device__ __forceinline__ unsigned enc_f32(float f) {
    unsigned u = __float_as_uint(f);
    return (u & 0x80000000u) ? ~u : (u | 0x80000000u);
}
__device__ __forceinline__ float dec_f32(unsigned u) {
    return (u & 0x80000000u) ? __uint_as_float(u & 0x7FFFFFFFu)
                             : __uint_as_float(~u);
}

__global__ __launch_bounds__(128)
void chamfer_pack_kernel(const float* __restrict__ a,
                         const float* __restrict__ b,
                         const int* __restrict__ a_idx,
                         const int* __restrict__ b_idx,
                         float4* __restrict__ pa4,
                         float4* __restrict__ pb4,
                         unsigned* __restrict__ minarr,
                         float* __restrict__ out,
                         int N, int n) {
    int i = blockIdx.x * 128 + threadIdx.x;   // 64 blocks x 128 threads
    if (i < n) {
        int ai = a_idx[i];
        float x = a[ai], y = a[N + ai], z = a[2 * N + ai];
        pa4[i] = make_float4(x, y, z, x * x + y * y + z * z);
        int bi = b_idx[i];
        float u = b[bi], v = b[N + bi], w = b[2 * N + bi];
        pb4[i] = make_float4(-2.f * u, -2.f * v, -2.f * w,
                             u * u + v * v + w * w);
        minarr[i] = 0xFFFFFFFFu;            // encoded +max
    }
    if (i == 0) out[0] = 0.f;               // d_out is poisoned each iter
}

__global__ __launch_bounds__(BLOCK)
void chamfer_min_kernel(const float4* __restrict__ pa4,
                        const float4* __restrict__ pb4,
                        unsigned* __restrict__ minarr,
                        int a_chunks) {
    __shared__ float4 tile[BPTS];
    const int bid = blockIdx.x;
    const int ac  = bid % a_chunks;
    const int bc  = bid / a_chunks;
    const int tid = threadIdx.x;
    const int APB = BLOCK * NPTS_A;          // a-points per block (1024)

    if (tid < BPTS)
        tile[tid] = pb4[bc * BPTS + tid];    // coalesced float4 copy
    __syncthreads();

    float ax[NPTS_A], ay[NPTS_A], az[NPTS_A], mn[NPTS_A];
#pragma unroll
    for (int m = 0; m < NPTS_A; ++m) {
        float4 p = pa4[ac * APB + m * BLOCK + tid];   // coalesced float4
        ax[m] = p.x; ay[m] = p.y; az[m] = p.z;
        mn[m] = 3.4e38f;
    }

    // 1 broadcast ds_read_b128 per k serves 4 a-points x 4 VALU ops.
#pragma unroll 8
    for (int k = 0; k < BPTS; ++k) {
        float4 t = tile[k];
#pragma unroll
        for (int m = 0; m < NPTS_A; ++m) {
            float c = fmaf(t.x, ax[m], fmaf(t.y, ay[m], fmaf(t.z, az[m], t.w)));
            mn[m] = fminf(mn[m], c);
        }
    }

    // Fire-and-forget (no return value -> no wait), coalesced across lanes.
#pragma unroll
    for (int m = 0; m < NPTS_A; ++m)
        atomicMin(&minarr[ac * APB + m * BLOCK + tid], enc_f32(mn[m]));
}

__global__ __launch_bounds__(BLOCK)
void chamfer_reduce_kernel(const float4* __restrict__ pa4,
                           const unsigned* __restrict__ minarr,
                           float* __restrict__ out) {
    __shared__ float wsum[BLOCK / 64];
    const int tid = threadIdx.x;
    const int i = blockIdx.x * BLOCK + tid;

    float v = dec_f32(minarr[i]) + pa4[i].w;

#pragma unroll
    for (int off = 32; off > 0; off >>= 1)
        v += __shfl_down(v, off, 64);
    if ((tid & 63) == 0) wsum[tid >> 6] = v;
    __syncthreads();
    if (tid == 0) {
        float s = 0.f;
#pragma unroll
        for (int w = 0; w < BLOCK / 64; ++w) s += wsum[w];
        atomicAdd(out, s);                   // out pre-zeroed by pack kernel
    }
}

extern "C" void kernel_launch(void* const* d_in, const int* in_sizes, int n_in,
                              void* d_out, int out_size, void* d_ws, size_t ws_size,
                              hipStream_t stream) {
    const float* a     = (const float*)d_in[0];
    const float* b     = (const float*)d_in[1];
    const int*   a_idx = (const int*)d_in[2];
    const int*   b_idx = (const int*)d_in[3];
    float*       out   = (float*)d_out;

    const int N = in_sizes[0] / 3;   // 16384
    const int n = in_sizes[2];       // 8192

    const int a_chunks = n / (BLOCK * NPTS_A);   // 8

    // ws layout: pa4 [n], pb4 [n], minarr [n]
    float4*   pa4    = (float4*)d_ws;
    float4*   pb4    = pa4 + n;
    unsigned* minarr = (unsigned*)(pb4 + n);

    chamfer_pack_kernel<<<n / 128, 128, 0, stream>>>(
        a, b, a_idx, b_idx, pa4, pb4, minarr, out, N, n);

    chamfer_min_kernel<<<a_chunks * (n / BPTS), BLOCK, 0, stream>>>(
        pa4, pb4, minarr, a_chunks);

    chamfer_reduce_kernel<<<n / BLOCK, BLOCK, 0, stream>>>(
        pa4, minarr, out);
}